// Round 2
// 250.350 us; speedup vs baseline: 1.0178x; 1.0178x over previous
//
#include <hip/hip_runtime.h>
#include <math.h>

// AttentionCropLayer v4 (resubmit; round-1 failure was container-level, no
// kernel diagnostic): one block per (b,c); 4 row-tiles computed sequentially
// with double-buffered ASYNC staging (global_load_lds, 16B) so the stage of
// tile t+1 overlaps the compute of tile t. Coefficient tables built once per
// (b,c) instead of once per tile.
//
// Staging is linear (wave-uniform LDS base + lane*16B, as global_load_lds
// requires): the crop's column window is widened to a float4-aligned start
// cs4 = colstart & ~3 (keeps every global src 16B-aligned), and the old
// per-element column clamp is dropped -- pad slots read finite in-image
// neighbors (flat-index min keeps reads inside this (b,c) image) and carry
// exactly-0.0f weights, so outputs are bit-identical.
//
// Key facts: tl in [38,55] -> in_size=2*tl in [76,110]; crop always fully
// inside the 224x224 image. Upscale factor in_size/224 <= 0.492, so 4
// consecutive output columns sample from <= 4 consecutive input columns.

constexpr int IMG = 224;
constexpr int OUT_ROWS = 56;           // output rows per tile
constexpr int TILES = IMG / OUT_ROWS;  // 4
constexpr int THREADS = 448;           // 7 waves; 56 col-groups x 8 rows
constexpr int S = 116;                 // LDS row stride (floats) = 29 float4
constexpr int SLOTS = 2 * THREADS;     // 896 float4 slots/buffer (>=30 rows)

__device__ __forceinline__ float sigm10(float z) {
    return 1.0f / (1.0f + expf(-10.0f * z));
}

// Bilinear (align_corners=False) source indices for output j. Exact
// reference fp32 arithmetic (_rn blocks FMA contraction / fast-div so the
// floor/trunc boundaries match the reference bit-for-bit).
__device__ __forceinline__ void bilin_idx(int j, int tl, int& i0, int& i1, float& w) {
    const int in_size = 2 * tl;
    float src = __fsub_rn(
        __fdiv_rn(__fmul_rn((float)j + 0.5f, (float)in_size), 224.0f), 0.5f);
    src = fmaxf(src, 0.0f);
    i0 = (int)floorf(src);
    w = __fsub_rn(src, (float)i0);
    i1 = min(i0 + 1, in_size - 1);
}

__device__ __forceinline__ void coeffs(int j, int t, int tl,
                                       int& p0, int& p1,
                                       float& w0, float& w1) {
    int i0, i1; float w;
    bilin_idx(j, tl, i0, i1, w);
    const int start = t - tl;
    p0 = start + i0;
    p1 = start + i1;
    const float tlf = (float)tl;
    const float d0 = (float)(p0 - t);
    const float d1 = (float)(p1 - t);
    const float m0 = sigm10(d0 + tlf) - sigm10(d0 - tlf);
    const float m1 = sigm10(d1 + tlf) - sigm10(d1 - tlf);
    w0 = (1.0f - w) * m0;
    w1 = w * m1;
}

// Async-stage one tile's crop rows into LDS. Wave-uniform LDS base, per-lane
// 16B-aligned global src. slot -> (row, col4) over a 29-float4-wide row;
// flat-index clamp keeps every read inside this (b,c) image (clamped slots
// are never referenced with non-zero weight).
__device__ __forceinline__ void stage_tile(const float* __restrict__ inb,
                                           float* buf, int loT, int cs4,
                                           int wavebase, int lane) {
#pragma unroll
    for (int p = 0; p < 2; ++p) {
        const int sb   = p * THREADS + wavebase;   // wave-uniform slot base
        const int slot = sb + lane;
        const int r    = slot / 29;                // const divisor -> magic mul
        const int c4   = slot - r * 29;
        int idx = (loT + r) * IMG + cs4 + 4 * c4;
        idx = min(idx, IMG * IMG - 4);             // stay inside this image
        __builtin_amdgcn_global_load_lds(
            (const __attribute__((address_space(1))) void*)(inb + idx),
            (__attribute__((address_space(3))) void*)(buf + sb * 4),
            16, 0, 0);
    }
}

__global__ __launch_bounds__(THREADS)
void attn_crop_kernel(const float* __restrict__ apn,
                      const float* __restrict__ in,
                      float* __restrict__ out) {
    __shared__ __align__(16) float simg[2][SLOTS * 4];  // 2 x 14.3 KB
    __shared__ float4 colc[IMG];   // {w0, w1, c0-cs4, c1-cs4}
    __shared__ float4 rowc[IMG];   // {a, bw, r0*S, r1*S} (absolute rows)

    const int tid = threadIdx.x;
    const int bc  = blockIdx.x;                // b*3 + c
    const int b   = bc / 3;

    const float a0 = apn[b * 3 + 0];
    const float a1 = apn[b * 3 + 1];
    const float a2 = apn[b * 3 + 2];
    const int tx = 112 + (int)truncf(__fadd_rn(__fmul_rn(a0, 56.0f), 0.5f));
    const int ty = 112 + (int)truncf(__fadd_rn(__fmul_rn(a1, 56.0f), 0.5f));
    const int tl = 38 + (int)truncf(
        __fmul_rn(__fmul_rn(__fadd_rn(a2, 1.0f), 0.5f), 18.0f));
    const int rowstart = tx - tl;
    const int colstart = ty - tl;
    const int cs4 = colstart & ~3;             // 16B-aligned column window

    // First staged input row of each tile.
    int loT[TILES];
#pragma unroll
    for (int t = 0; t < TILES; ++t) {
        int i0, i1; float w;
        bilin_idx(t * OUT_ROWS, tl, i0, i1, w);
        loT[t] = rowstart + i0;
    }

    // Phase A: coefficient tables, once per (b,c). 448 threads = 224 + 224.
    if (tid < IMG) {
        int c0, c1; float w0, w1;
        coeffs(tid, ty, tl, c0, c1, w0, w1);
        float4 cc;
        cc.x = w0;
        cc.y = w1;
        cc.z = __int_as_float(c0 - cs4);
        cc.w = __int_as_float(c1 - cs4);
        colc[tid] = cc;
    } else {
        const int j = tid - IMG;
        int r0, r1; float w0, w1;
        coeffs(j, tx, tl, r0, r1, w0, w1);
        float4 rc;
        rc.x = w0;                             // a
        rc.y = w1;                             // bw
        rc.z = __int_as_float(r0 * S);
        rc.w = __int_as_float(r1 * S);
        rowc[j] = rc;
    }

    const float* inb = in + (size_t)bc * (IMG * IMG);
    const int wavebase = tid & ~63;
    const int lane     = tid & 63;

    stage_tile(inb, simg[0], loT[0], cs4, wavebase, lane);
    __syncthreads();   // drains stage-0 DMA + publishes tables

    // Per-thread column-group setup (constant across tiles).
    const int g    = tid % 56;
    const int rloc = tid / 56;

    const float4 cc0 = colc[4 * g + 0];
    const float4 cc1 = colc[4 * g + 1];
    const float4 cc2 = colc[4 * g + 2];
    const float4 cc3 = colc[4 * g + 3];
    const int base = __float_as_int(cc0.z);    // segment base (local col)

    float4 wv0, wv1, wv2, wv3;
#define BUILD(WV, CC)                                                     \
    {                                                                     \
        const int o0 = __float_as_int(CC.z) - base;                       \
        const int o1 = __float_as_int(CC.w) - base;                       \
        const float w0 = CC.x, w1 = CC.y;                                 \
        WV.x = (o0 == 0 ? w0 : 0.0f) + (o1 == 0 ? w1 : 0.0f);             \
        WV.y = (o0 == 1 ? w0 : 0.0f) + (o1 == 1 ? w1 : 0.0f);             \
        WV.z = (o0 == 2 ? w0 : 0.0f) + (o1 == 2 ? w1 : 0.0f);             \
        WV.w = (o0 == 3 ? w0 : 0.0f) + (o1 == 3 ? w1 : 0.0f);             \
    }
    BUILD(wv0, cc0)
    BUILD(wv1, cc1)
    BUILD(wv2, cc2)
    BUILD(wv3, cc3)
#undef BUILD

    float* outg = out + (size_t)bc * (IMG * IMG) + 4 * g;

#pragma unroll
    for (int t = 0; t < TILES; ++t) {
        const float* buf = simg[t & 1];
        if (t + 1 < TILES)   // prefetch next tile; overlaps compute below
            stage_tile(inb, simg[(t + 1) & 1], loT[t + 1], cs4, wavebase, lane);

        const int j0  = t * OUT_ROWS;
        const int adj = base - loT[t] * S;     // absolute r*S -> local offset
        float* outb = outg + (size_t)j0 * IMG;

#pragma unroll
        for (int pass = 0; pass < OUT_ROWS / 8; ++pass) {
            const int row = pass * 8 + rloc;
            const float4 rc = rowc[j0 + row];  // 2 addresses/wave LDS read
            const float a  = rc.x;
            const float bw = rc.y;
            const float* s0 = buf + __float_as_int(rc.z) + adj;
            const float* s1 = buf + __float_as_int(rc.w) + adj;

            // Row blend first (independent of column), then 4-tap col dots.
            const float m0 = a * s0[0] + bw * s1[0];
            const float m1 = a * s0[1] + bw * s1[1];
            const float m2 = a * s0[2] + bw * s1[2];
            const float m3 = a * s0[3] + bw * s1[3];

            float4 o;
            o.x = wv0.x * m0 + wv0.y * m1 + wv0.z * m2 + wv0.w * m3;
            o.y = wv1.x * m0 + wv1.y * m1 + wv1.z * m2 + wv1.w * m3;
            o.z = wv2.x * m0 + wv2.y * m1 + wv2.z * m2 + wv2.w * m3;
            o.w = wv3.x * m0 + wv3.y * m1 + wv3.z * m2 + wv3.w * m3;

            *(float4*)(outb + row * IMG) = o;  // coalesced 16B store
        }
        if (t + 1 < TILES)
            __syncthreads();  // next buffer staged; prev buffer reads done
    }
}

extern "C" void kernel_launch(void* const* d_in, const int* in_sizes, int n_in,
                              void* d_out, int out_size, void* d_ws, size_t ws_size,
                              hipStream_t stream) {
    const float* apn = (const float*)d_in[0];   // (256, 3)
    const float* in  = (const float*)d_in[1];   // (256, 3, 224, 224)
    float* out = (float*)d_out;                 // (256, 3, 224, 224)

    const int B = in_sizes[0] / 3;              // 256
    const int grid = B * 3;                     // 768 blocks = 3 per CU
    attn_crop_kernel<<<grid, THREADS, 0, stream>>>(apn, in, out);
}

// Round 3
// 249.929 us; speedup vs baseline: 1.0195x; 1.0017x over previous
//
#include <hip/hip_runtime.h>
#include <math.h>

// AttentionCropLayer v5: one block per (b,c,half). Stage the ENTIRE half-crop
// via async global_load_lds (4 x 16B per thread), build coeff tables, then a
// SINGLE __syncthreads(), then 14 compute passes with fire-and-forget stores.
//
// Why: v4's per-tile __syncthreads() forced s_waitcnt vmcnt(0) which drains
// the output STORES too -- 4 store-drain stalls per block with only 21
// waves/CU to hide them (kernel ~2x the 32us HBM floor). v5 has exactly one
// barrier (stage DMA + tables), stores are never waited on, and 4 resident
// blocks/CU (28 waves, 87.5% occupancy) hide each block's one staging
// latency.
//
// Key facts: tl in [38,55] -> in_size=2*tl in [76,110]; crop fully inside
// the 224x224 image; upscale <= 0.492 so 4 output cols <- <=4 input cols,
// and a 112-row output half reads <= 57 input rows (staged 61, clamped).

constexpr int IMG = 224;
constexpr int HALF_ROWS = 112;         // output rows per block
constexpr int THREADS = 448;           // 7 waves; 56 col-groups x 8 rows
constexpr int S = 116;                 // LDS row stride (floats) = 29 float4
constexpr int SLOTS = 4 * THREADS;     // 1792 float4 slots = 61 rows staged

__device__ __forceinline__ float sigm10(float z) {
    return 1.0f / (1.0f + expf(-10.0f * z));
}

// Bilinear (align_corners=False) source indices for output j. Exact
// reference fp32 arithmetic (_rn blocks FMA contraction / fast-div so the
// floor/trunc boundaries match the reference bit-for-bit).
__device__ __forceinline__ void bilin_idx(int j, int tl, int& i0, int& i1, float& w) {
    const int in_size = 2 * tl;
    float src = __fsub_rn(
        __fdiv_rn(__fmul_rn((float)j + 0.5f, (float)in_size), 224.0f), 0.5f);
    src = fmaxf(src, 0.0f);
    i0 = (int)floorf(src);
    w = __fsub_rn(src, (float)i0);
    i1 = min(i0 + 1, in_size - 1);
}

__device__ __forceinline__ void coeffs(int j, int t, int tl,
                                       int& p0, int& p1,
                                       float& w0, float& w1) {
    int i0, i1; float w;
    bilin_idx(j, tl, i0, i1, w);
    const int start = t - tl;
    p0 = start + i0;
    p1 = start + i1;
    const float tlf = (float)tl;
    const float d0 = (float)(p0 - t);
    const float d1 = (float)(p1 - t);
    const float m0 = sigm10(d0 + tlf) - sigm10(d0 - tlf);
    const float m1 = sigm10(d1 + tlf) - sigm10(d1 - tlf);
    w0 = (1.0f - w) * m0;
    w1 = w * m1;
}

__global__ __launch_bounds__(THREADS)
void attn_crop_kernel(const float* __restrict__ apn,
                      const float* __restrict__ in,
                      float* __restrict__ out) {
    __shared__ __align__(16) float simg[SLOTS * 4];  // 28.0 KB staged crop
    __shared__ float4 colc[IMG];        // {w0, w1, c0-cs4, c1-cs4}
    __shared__ float4 rowc[HALF_ROWS];  // {a, bw, r0*S, r1*S} (absolute rows)

    const int tid  = threadIdx.x;
    const int bid  = blockIdx.x;
    const int half = bid & 1;
    const int bc   = bid >> 1;                 // b*3 + c
    const int b    = bc / 3;

    const float a0 = apn[b * 3 + 0];
    const float a1 = apn[b * 3 + 1];
    const float a2 = apn[b * 3 + 2];
    const int tx = 112 + (int)truncf(__fadd_rn(__fmul_rn(a0, 56.0f), 0.5f));
    const int ty = 112 + (int)truncf(__fadd_rn(__fmul_rn(a1, 56.0f), 0.5f));
    const int tl = 38 + (int)truncf(
        __fmul_rn(__fmul_rn(__fadd_rn(a2, 1.0f), 0.5f), 18.0f));
    const int rowstart = tx - tl;
    const int colstart = ty - tl;
    const int cs4 = colstart & ~3;             // 16B-aligned column window
    const int j0  = half * HALF_ROWS;

    // First staged input row of this half.
    int loT;
    {
        int i0, i1; float w;
        bilin_idx(j0, tl, i0, i1, w);
        loT = rowstart + i0;
    }

    // Phase A: coefficient tables (once per block). 224 + 112 threads.
    if (tid < IMG) {
        int c0, c1; float w0, w1;
        coeffs(tid, ty, tl, c0, c1, w0, w1);
        float4 cc;
        cc.x = w0;
        cc.y = w1;
        cc.z = __int_as_float(c0 - cs4);
        cc.w = __int_as_float(c1 - cs4);
        colc[tid] = cc;
    } else if (tid < IMG + HALF_ROWS) {
        const int j = j0 + (tid - IMG);
        int r0, r1; float w0, w1;
        coeffs(j, tx, tl, r0, r1, w0, w1);
        float4 rc;
        rc.x = w0;                             // a
        rc.y = w1;                             // bw
        rc.z = __int_as_float(r0 * S);
        rc.w = __int_as_float(r1 * S);
        rowc[tid - IMG] = rc;
    }

    // Phase B: async-stage the whole half-crop. Wave-uniform LDS base +
    // lane*16B (global_load_lds contract); per-lane 16B-aligned global src.
    // Flat-index clamp keeps reads inside this (b,c) image; clamped slots
    // are only ever multiplied by exact 0.0f weights.
    const float* inb = in + (size_t)bc * (IMG * IMG);
    const int wavebase = tid & ~63;
    const int lane     = tid & 63;
#pragma unroll
    for (int p = 0; p < 4; ++p) {
        const int sb   = p * THREADS + wavebase;   // wave-uniform slot base
        const int slot = sb + lane;
        const int r    = slot / 29;                // const divisor -> magic mul
        const int c4   = slot - r * 29;
        int idx = (loT + r) * IMG + cs4 + 4 * c4;
        idx = min(idx, IMG * IMG - 4);             // stay inside this image
        __builtin_amdgcn_global_load_lds(
            (const __attribute__((address_space(1))) void*)(inb + idx),
            (__attribute__((address_space(3))) void*)(simg + sb * 4),
            16, 0, 0);
    }

    __syncthreads();   // the ONLY barrier: drains stage DMA, publishes tables

    // Phase C: g = column group (4 output cols), rloc = row slot within pass.
    const int g    = tid % 56;
    const int rloc = tid / 56;

    const float4 cc0 = colc[4 * g + 0];
    const float4 cc1 = colc[4 * g + 1];
    const float4 cc2 = colc[4 * g + 2];
    const float4 cc3 = colc[4 * g + 3];
    const int base = __float_as_int(cc0.z);    // segment base (local col)

    float4 wv0, wv1, wv2, wv3;
#define BUILD(WV, CC)                                                     \
    {                                                                     \
        const int o0 = __float_as_int(CC.z) - base;                       \
        const int o1 = __float_as_int(CC.w) - base;                       \
        const float w0 = CC.x, w1 = CC.y;                                 \
        WV.x = (o0 == 0 ? w0 : 0.0f) + (o1 == 0 ? w1 : 0.0f);             \
        WV.y = (o0 == 1 ? w0 : 0.0f) + (o1 == 1 ? w1 : 0.0f);             \
        WV.z = (o0 == 2 ? w0 : 0.0f) + (o1 == 2 ? w1 : 0.0f);             \
        WV.w = (o0 == 3 ? w0 : 0.0f) + (o1 == 3 ? w1 : 0.0f);             \
    }
    BUILD(wv0, cc0)
    BUILD(wv1, cc1)
    BUILD(wv2, cc2)
    BUILD(wv3, cc3)
#undef BUILD

    // Absolute r0*S -> local LDS offset, constant per block.
    const float* bufadj = simg + (base - loT * S);
    float* outb = out + (size_t)bc * (IMG * IMG) + (size_t)j0 * IMG + 4 * g;

#pragma unroll
    for (int pass = 0; pass < HALF_ROWS / 8; ++pass) {
        const int row = pass * 8 + rloc;
        const float4 rc = rowc[row];           // 2 addresses/wave LDS read
        const float a  = rc.x;
        const float bw = rc.y;
        const float* s0 = bufadj + __float_as_int(rc.z);
        const float* s1 = bufadj + __float_as_int(rc.w);

        // Row blend first (independent of column), then 4-tap column dots.
        const float m0 = a * s0[0] + bw * s1[0];
        const float m1 = a * s0[1] + bw * s1[1];
        const float m2 = a * s0[2] + bw * s1[2];
        const float m3 = a * s0[3] + bw * s1[3];

        float4 o;
        o.x = wv0.x * m0 + wv0.y * m1 + wv0.z * m2 + wv0.w * m3;
        o.y = wv1.x * m0 + wv1.y * m1 + wv1.z * m2 + wv1.w * m3;
        o.z = wv2.x * m0 + wv2.y * m1 + wv2.z * m2 + wv2.w * m3;
        o.w = wv3.x * m0 + wv3.y * m1 + wv3.z * m2 + wv3.w * m3;

        *(float4*)(outb + row * IMG) = o;      // coalesced, never waited on
    }
}

extern "C" void kernel_launch(void* const* d_in, const int* in_sizes, int n_in,
                              void* d_out, int out_size, void* d_ws, size_t ws_size,
                              hipStream_t stream) {
    const float* apn = (const float*)d_in[0];   // (256, 3)
    const float* in  = (const float*)d_in[1];   // (256, 3, 224, 224)
    float* out = (float*)d_out;                 // (256, 3, 224, 224)

    const int B = in_sizes[0] / 3;              // 256
    const int grid = B * 3 * 2;                 // 1536 blocks; 4 resident/CU
    attn_crop_kernel<<<grid, THREADS, 0, stream>>>(apn, in, out);
}